// Round 14
// baseline (490.889 us; speedup 1.0000x reference)
//
#include <hip/hip_runtime.h>

// Self-attention, B=4, N=4096, D=256 (single head over full D).
//   Q = x Wq^T + bq ; K,V likewise ; S = Q K^T ; mask==0 -> -inf ;
//   attn = softmax(S/16) ; out = attn V        (fp32 in/out)
// R24 = R21 revert (482us total, flash 165.5us, PASSED) + s_setprio
//   around MFMA clusters (zero-risk hint; T5).
// History: R22/R23 (V staged one-ahead) failed absmax 4.9e-3 -- third
//   failure of a freshly-derived deep-queue wait scheme (R14, R18, R23)
//   vs 3/3 passes for minimal-delta schemes (R17, R19, R21). On-paper
//   FIFO/WAR proofs check out each time => my vmcnt model is missing a
//   HW behavior; abandoning that lever (no bisection possible here).
// R21 (proven): K double-buffered, staged at tile TOP into the alternate
//   buffer; V single-buffered, staged at TOP, waited at E. Per tile t:
//   TOP stage V(t)->Vlds (4) + K(t+1)->Klds[(t+1)&1] (4) ->
//   QK from Klds[t&1] -> P=exp2(masked S) (mask regs) -> B2 (lgkm0+bar)
//   -> M(t+2) NT -> E vmcnt(12)+bar [retires M(t+1)+V(t)] -> PV -> B1
//   vmcnt(8)+bar [K(t+1) landed; M(t+2) flies].
// ws: Qs bf16 8MiB | Kb bf16 8MiB | Vt bf16 8MiB | Wp 384KiB

#define DEV static __device__ __forceinline__

typedef __attribute__((ext_vector_type(8))) short bf8;   // 8 bf16 (4 VGPR)
typedef __attribute__((ext_vector_type(4))) float f4;
typedef const __attribute__((address_space(1))) unsigned int* gp1;
typedef __attribute__((address_space(3))) unsigned int* lp3;

DEV short f2bf(float x) {  // fp32 -> bf16 RNE (inputs finite)
  unsigned u = __builtin_bit_cast(unsigned, x);
  u += 0x7FFFu + ((u >> 16) & 1u);
  return (short)(u >> 16);
}

DEV bf8 cvt8(f4 a, f4 b) {
  bf8 r;
  r[0] = f2bf(a[0]); r[1] = f2bf(a[1]); r[2] = f2bf(a[2]); r[3] = f2bf(a[3]);
  r[4] = f2bf(b[0]); r[5] = f2bf(b[1]); r[6] = f2bf(b[2]); r[7] = f2bf(b[3]);
  return r;
}

DEV bf8 cvtp(const float* p) { return cvt8(*(const f4*)p, *(const f4*)(p + 4)); }

DEV f4 mfma16(bf8 a, bf8 b, f4 c) {
  return __builtin_amdgcn_mfma_f32_16x16x32_bf16(a, b, c, 0, 0, 0);
}

DEV void gl_lds16(const void* g, void* l) {  // async global->LDS, 16B/lane
  __builtin_amdgcn_global_load_lds((gp1)g, (lp3)l, 16, 0, 0);
}

DEV void ld16(bf8& d, const short* p) {  // unsinkable 16B global load
  __asm__ __volatile__("global_load_dwordx4 %0, %1, off" : "=v"(d) : "v"(p));
}
DEV void ld4nt(int& d, const int* p) {   // unsinkable 4B global load, NT
  __asm__ __volatile__("global_load_dword %0, %1, off nt" : "=v"(d) : "v"(p));
}

// ---------------- kernel 0: pack W -> bf16 fragment-order (R9) ------------
__global__ void pack(const float* __restrict__ Wq, const float* __restrict__ Wk,
                     const float* __restrict__ Wv, short* __restrict__ Wp) {
  const int ch = blockIdx.x * 4 + (threadIdx.x >> 6);
  const int lane = threadIdx.x & 63;
  const int which = ch >> 7, rem = ch & 127;
  const int w = rem >> 5, e = (rem >> 3) & 3, ks = rem & 7;
  const float* W = (which == 0) ? Wq : (which == 1) ? Wk : Wv;
  bf8 v = cvtp(W + ((w * 4 + e) * 16 + (lane & 15)) * 256 + ks * 32 +
               (lane >> 4) * 8);
  *(bf8*)(Wp + ch * 512 + lane * 8) = v;
}

// ---------------- kernel 1: Q,K,V projection (R9) -------------------------
__launch_bounds__(256, 3)
__global__ void qkv(const float* __restrict__ x, const short* __restrict__ Wp,
                    const float* __restrict__ bq, const float* __restrict__ bk,
                    const float* __restrict__ bv, short* __restrict__ Qs,
                    short* __restrict__ Kb, short* __restrict__ Vt) {
  __shared__ float Xf[32 * 256];    // x tile, swizzled, 32KB
  __shared__ short Vlds[256 * 36];  // V transpose staging (which==2 only)
  const int which = blockIdx.y;
  const int m0 = blockIdx.x * 32;
  const int tid = threadIdx.x;
  const int w = tid >> 6, lane = tid & 63, quad = lane >> 4, c = lane & 15;
  const float* bias = (which == 0) ? bq : (which == 1) ? bk : bv;

#pragma unroll
  for (int l = 0; l < 8; l++) {
    const int row = l * 4 + (tid >> 6);
    const int kch = tid & 63;
    const int chg = (kch & 48) | ((kch ^ (row & 15)) & 15);  // involutive
    gl_lds16(x + (m0 + row) * 256 + chg * 4, &Xf[(l * 256 + tid) * 4]);
  }

  float bb[4];
#pragma unroll
  for (int e = 0; e < 4; e++) bb[e] = bias[(w * 4 + e) * 16 + c];

  f4 acc[2][4];
  const f4 z = {0.f, 0.f, 0.f, 0.f};
#pragma unroll
  for (int i = 0; i < 2; i++)
#pragma unroll
    for (int j = 0; j < 4; j++) acc[i][j] = z;

  __asm__ __volatile__("s_waitcnt vmcnt(0)\ns_barrier" ::: "memory");

  const short* wpb = Wp + (which * 4 + w) * 4 * 8 * 512;
#pragma unroll
  for (int ks = 0; ks < 8; ks++) {
    bf8 a[2], b[4];
#pragma unroll
    for (int ms = 0; ms < 2; ms++) {  // A[m=lane&15][k=quad*8+j]
      const int m = ms * 16 + c;
      const int ch0 = ks * 8 + quad * 2;
      const int sw0 = (ch0 & 48) | ((ch0 ^ c) & 15);
      const int sw1 = ((ch0 + 1) & 48) | (((ch0 + 1) ^ c) & 15);
      f4 f0 = *(const f4*)&Xf[m * 256 + sw0 * 4];
      f4 f1 = *(const f4*)&Xf[m * 256 + sw1 * 4];
      a[ms] = cvt8(f0, f1);
    }
#pragma unroll
    for (int e = 0; e < 4; e++)
      b[e] = *(const bf8*)(wpb + (e * 8 + ks) * 512 + lane * 8);
#pragma unroll
    for (int ms = 0; ms < 2; ms++)
#pragma unroll
      for (int e = 0; e < 4; e++) acc[ms][e] = mfma16(a[ms], b[e], acc[ms][e]);
  }

  const float sc = (which == 0) ? 0.09016844005556021f : 1.0f;  // log2e/16

  if (which < 2) {
    short* dst = (which == 0) ? Qs : Kb;
#pragma unroll
    for (int ms = 0; ms < 2; ms++)
#pragma unroll
      for (int e = 0; e < 4; e++)
#pragma unroll
        for (int r = 0; r < 4; r++)  // C/D: col=lane&15, row=quad*4+reg
          dst[(m0 + ms * 16 + quad * 4 + r) * 256 + (w * 4 + e) * 16 + c] =
              f2bf((acc[ms][e][r] + bb[e]) * sc);
  } else {
#pragma unroll
    for (int ms = 0; ms < 2; ms++)
#pragma unroll
      for (int e = 0; e < 4; e++)
#pragma unroll
        for (int r = 0; r < 4; r++)
          Vlds[((w * 4 + e) * 16 + c) * 36 + ms * 16 + quad * 4 + r] =
              f2bf(acc[ms][e][r] + bb[e]);
    __syncthreads();
    const int tt = m0 >> 6, half = m0 & 32;
#pragma unroll
    for (int j = 0; j < 4; j++) {
      int flat = j * 2048 + tid * 8;        // 256 d x 32 n
      int d = flat >> 5, n = flat & 31;
      *(bf8*)(Vt + tt * 16384 + d * 64 + half + n) =
          *(const bf8*)&Vlds[d * 36 + n];
    }
  }
}

// ---------------- kernel 2: flash attention ----------------
// 256 WGs x 512 threads (8 waves, 1 block/CU). batch = (bx&7)>>1,
// q0 = ((bx>>3)*2+(bx&1))*64 (bijective). Wave w8: h = w8>>2 (q-rows
// h*32..+31), wc = w8&3 (cols wc*64..+63 for PV/out, k-cols wc*16..+15).
// K double-buffered; V single; per tile t:
//  TOP: stage V(t)->Vlds (4) + K(t+1)->Klds[(t+1)&1] (4) ->
//  QK from Klds[t&1] -> P=exp2(masked S) (mask regs) -> B2 (lgkm0+bar)
//  -> issue M(t+2) NT -> E vmcnt(12)+bar [retires M(t+1)+V(t); K+M fly]
//  -> PV (V,P from LDS) -> B1 vmcnt(8)+bar [K(t+1) landed; M(t+2) flies].
// s_setprio(1) wraps the QK and PV MFMA clusters (scheduler hint only).
__launch_bounds__(512, 1)
__global__ void flash(const short* __restrict__ Qs, const short* __restrict__ Kb,
                      const short* __restrict__ Vt, const int* __restrict__ mask,
                      float* __restrict__ out) {
  __shared__ short Klds[2][16384];  // K dbuf 64x256, swizzled, 64KB
  __shared__ short Vlds[16384];     // V [256 d][64 k], swizzled, 32KB
  __shared__ short Plds[64 * 76];   // P 64 rows, stride 76 (conflict-free)
  const int bx = blockIdx.x;
  const int batch = (bx & 7) >> 1;                  // XCD pair -> batch
  const int q0 = ((bx >> 3) * 2 + (bx & 1)) * 64;   // bijective q-tile
  const int tid = threadIdx.x;
  const int lane = tid & 63, quad = lane >> 4, c = lane & 15;
  const int w8 = tid >> 6, h = w8 >> 2, wc = w8 & 3;

  const short* kb = Kb + batch * 4096 * 256;
  const short* vb = Vt + batch * 1048576;
  const int* mb = mask + batch * 16777216;

  const int krow = tid >> 5;  // K staging row-in-16-row-line (0..15)
  const int kch = tid & 31;   // LDS chunk this thread fills

  // ---- prologue: K(0)->Klds[0], M(0)->mA, M(1)->mB, Q via asm ----
#pragma unroll
  for (int l = 0; l < 4; l++) {
    const int row = l * 16 + krow;
    const int chg = (kch & 16) | ((kch ^ row) & 15);  // involutive swizzle
    gl_lds16(kb + row * 256 + chg * 8, &Klds[0][l * 4096 + tid * 8]);
  }
  int mA[8], mB[8];
#pragma unroll
  for (int ms = 0; ms < 2; ms++)
#pragma unroll
    for (int r = 0; r < 4; r++) {
      const int qr = q0 + h * 32 + ms * 16 + quad * 4 + r;
      ld4nt(mA[ms * 4 + r], mb + qr * 4096 + wc * 16 + c);
      ld4nt(mB[ms * 4 + r], mb + qr * 4096 + 64 + wc * 16 + c);
    }
  bf8 aq[2][8];
  const short* qb = Qs + (batch * 4096 + q0) * 256;
#pragma unroll
  for (int ms = 0; ms < 2; ms++)
#pragma unroll
    for (int ks = 0; ks < 8; ks++)
      ld16(aq[ms][ks], qb + (h * 32 + ms * 16 + c) * 256 + ks * 32 + quad * 8);

  const f4 z = {0.f, 0.f, 0.f, 0.f};
  f4 accO[2][4], lacc[2];
#pragma unroll
  for (int ms = 0; ms < 2; ms++) {
    lacc[ms] = z;
#pragma unroll
    for (int ds = 0; ds < 4; ds++) accO[ms][ds] = z;
  }
  const bf8 ONES = {0x3F80, 0x3F80, 0x3F80, 0x3F80, 0x3F80, 0x3F80, 0x3F80, 0x3F80};

  // drain prologue; tie aq on the waitcnt, masks on a follow-up tie asm
  __asm__ __volatile__("s_waitcnt vmcnt(0)\ns_barrier"
      : "+v"(aq[0][0]), "+v"(aq[0][1]), "+v"(aq[0][2]), "+v"(aq[0][3]),
        "+v"(aq[0][4]), "+v"(aq[0][5]), "+v"(aq[0][6]), "+v"(aq[0][7]),
        "+v"(aq[1][0]), "+v"(aq[1][1]), "+v"(aq[1][2]), "+v"(aq[1][3]),
        "+v"(aq[1][4]), "+v"(aq[1][5]), "+v"(aq[1][6]), "+v"(aq[1][7])
      :: "memory");
  __asm__ __volatile__(""
      : "+v"(mA[0]), "+v"(mA[1]), "+v"(mA[2]), "+v"(mA[3]),
        "+v"(mA[4]), "+v"(mA[5]), "+v"(mA[6]), "+v"(mA[7]),
        "+v"(mB[0]), "+v"(mB[1]), "+v"(mB[2]), "+v"(mB[3]),
        "+v"(mB[4]), "+v"(mB[5]), "+v"(mB[6]), "+v"(mB[7]) :: "memory");

  auto tile = [&](int t, int* mcur) {
    // ---- TOP: stage V(t) -> Vlds (WAR safe: PV(t-1) reads done at
    //      B1(t-1)); then K(t+1) -> Klds[(t+1)&1] (WAR safe: that buffer
    //      last read at QK(t-1), complete at B2(t-1)). Issue order V
    //      before K keeps the E/B1 retire sets identical to R19. ----
    const short* vbt = vb + t * 16384;
#pragma unroll
    for (int l = 0; l < 4; l++) {
      const int flat = l * 512 + tid;      // 0..2047, 16B each
      const int d = flat >> 3, ck = flat & 7;
      gl_lds16(vbt + d * 64 + ((ck ^ (d & 7)) << 3), &Vlds[flat * 8]);
    }
    const int tk = (t < 63) ? t + 1 : 63;
    const short* kbt = kb + tk * 16384;
    short* kst = &Klds[(t + 1) & 1][0];
#pragma unroll
    for (int l = 0; l < 4; l++) {
      const int row = l * 16 + krow;
      const int chg = (kch & 16) | ((kch ^ row) & 15);
      gl_lds16(kbt + row * 256 + chg * 8, &kst[l * 4096 + tid * 8]);
    }

    // ---- S = Q' K^T from Klds[t&1] (proven landed at B1(t-1)) ----
    const short* krd = &Klds[t & 1][0];
    f4 s[2];
#pragma unroll
    for (int ms = 0; ms < 2; ms++) s[ms] = z;
    __builtin_amdgcn_s_setprio(1);
#pragma unroll
    for (int ks = 0; ks < 8; ks++) {
      const int ch = ks * 4 + quad;
      const int sw = (ch & 16) | ((ch ^ c) & 15);
      const bf8 kf = *(const bf8*)&krd[(wc * 16 + c) * 256 + sw * 8];
#pragma unroll
      for (int ms = 0; ms < 2; ms++) s[ms] = mfma16(aq[ms][ks], kf, s[ms]);
    }
    __builtin_amdgcn_s_setprio(0);

    // ---- P = exp2(masked S) -> Plds (mask regs retired by prev E) ----
    short* pw = &Plds[0];
#pragma unroll
    for (int ms = 0; ms < 2; ms++)
#pragma unroll
      for (int r = 0; r < 4; r++) {
        float sv = (mcur[ms * 4 + r] != 0) ? s[ms][r] : -INFINITY;
        pw[(h * 32 + ms * 16 + quad * 4 + r) * 76 + wc * 16 + c] =
            f2bf(__builtin_amdgcn_exp2f(sv));
      }
    // B2: P visible; all QK reads of Klds[t&1] complete across the block
    __asm__ __volatile__("s_waitcnt lgkmcnt(0)\ns_barrier" ::: "memory");

    // ---- issue M(t+2) into mcur (P reads above done; reg WAR orders) ----
    const int tm = (t + 2 < 64) ? t + 2 : 63;
#pragma unroll
    for (int ms = 0; ms < 2; ms++)
#pragma unroll
      for (int r = 0; r < 4; r++)
        ld4nt(mcur[ms * 4 + r],
              mb + (q0 + h * 32 + ms * 16 + quad * 4 + r) * 4096 + tm * 64 +
                  wc * 16 + c);

    // ---- E: queue=[M(t+1):8,V(t):4,K(t+1):4,M(t+2):8]=24; vmcnt(12)
    //      retires M(t+1)+V(t); leaves K4+M8 flying; barrier -> V(t)
    //      visible block-wide ----
    __asm__ __volatile__("s_waitcnt vmcnt(12)\ns_barrier"
        : "+v"(mA[0]), "+v"(mA[1]), "+v"(mA[2]), "+v"(mA[3]),
          "+v"(mA[4]), "+v"(mA[5]), "+v"(mA[6]), "+v"(mA[7]),
          "+v"(mB[0]), "+v"(mB[1]), "+v"(mB[2]), "+v"(mB[3]),
          "+v"(mB[4]), "+v"(mB[5]), "+v"(mB[6]), "+v"(mB[7]) :: "memory");

    // ---- O += P V ; row-sum via ones-frag MFMA. V frags from Vlds:
    //      lane reads Vlds[d=wc*64+ds*16+c][(k2*4+quad)^(c&7) chunk] ----
    __builtin_amdgcn_s_setprio(1);
#pragma unroll
    for (int k2 = 0; k2 < 2; k2++) {
      bf8 ap[2], vf[4];
#pragma unroll
      for (int ds = 0; ds < 4; ds++)
        vf[ds] = *(const bf8*)&Vlds[(wc * 64 + ds * 16 + c) * 64 +
                                    (((k2 * 4 + quad) ^ (c & 7)) << 3)];
#pragma unroll
      for (int ms = 0; ms < 2; ms++)  // A[m=lane&15][k=quad*8+j]
        ap[ms] = *(const bf8*)&pw[(h * 32 + ms * 16 + c) * 76 + k2 * 32 +
                                  quad * 8];
#pragma unroll
      for (int ms = 0; ms < 2; ms++) {
        lacc[ms] = mfma16(ap[ms], ONES, lacc[ms]);
#pragma unroll
        for (int ds = 0; ds < 4; ds++)
          accO[ms][ds] = mfma16(ap[ms], vf[ds], accO[ms][ds]);
      }
    }
    __builtin_amdgcn_s_setprio(0);
    // B1: vmcnt(8) retires K(t+1) (leaves M(t+2) flying); barrier ->
    // K(t+1) visible for next tile's QK; Vlds/Plds free for overwrite
    __asm__ __volatile__("s_waitcnt vmcnt(8)\ns_barrier" ::: "memory");
  };

  for (int th = 0; th < 32; th++) {
    tile(2 * th, mA);
    tile(2 * th + 1, mB);
  }
  // drain in-flight tail M loads before epilogue reuses their registers
  __asm__ __volatile__("s_waitcnt vmcnt(0)" ::: "memory");

  // ---- epilogue: O / l (in-register, deterministic) ----
  float* ob = out + (batch * 4096 + q0) * 256;
#pragma unroll
  for (int ms = 0; ms < 2; ms++) {
    f4 rl;
#pragma unroll
    for (int r = 0; r < 4; r++) rl[r] = __builtin_amdgcn_rcpf(lacc[ms][r]);
#pragma unroll
    for (int ds = 0; ds < 4; ds++)
#pragma unroll
      for (int r = 0; r < 4; r++)
        ob[(h * 32 + ms * 16 + quad * 4 + r) * 256 + wc * 64 + ds * 16 + c] =
            accO[ms][ds][r] * rl[r];
  }
}

extern "C" void kernel_launch(void* const* d_in, const int* in_sizes, int n_in,
                              void* d_out, int out_size, void* d_ws, size_t ws_size,
                              hipStream_t stream) {
  const float* x = (const float*)d_in[0];
  const int* mask = (const int*)d_in[1];
  const float* Wq = (const float*)d_in[2];
  const float* bq = (const float*)d_in[3];
  const float* Wk = (const float*)d_in[4];
  const float* bk = (const float*)d_in[5];
  const float* Wv = (const float*)d_in[6];
  const float* bv = (const float*)d_in[7];
  float* out = (float*)d_out;

  char* ws = (char*)d_ws;  // 24 MiB + 384 KiB
  short* Qs = (short*)ws;
  short* Kb = (short*)(ws + (8u << 20));
  short* Vt = (short*)(ws + (16u << 20));
  short* Wp = (short*)(ws + (24u << 20));

  pack<<<96, 256, 0, stream>>>(Wq, Wk, Wv, Wp);
  qkv<<<dim3(512, 3), 256, 0, stream>>>(x, Wp, bq, bk, bv, Qs, Kb, Vt);
  flash<<<256, 512, 0, stream>>>(Qs, Kb, Vt, mask, out);
}

// Round 15
// 480.249 us; speedup vs baseline: 1.0222x; 1.0222x over previous
//
#include <hip/hip_runtime.h>

// Self-attention, B=4, N=4096, D=256 (single head over full D).
//   Q = x Wq^T + bq ; K,V likewise ; S = Q K^T ; mask==0 -> -inf ;
//   attn = softmax(S/16) ; out = attn V        (fp32 in/out)
// R25 = R21 verbatim (session-best: 482.1us total, flash 165.5us).
//   R24's setprio was a measured regression (flash 165.5->174.4;
//   lockstep barrier schedule => setprio starves staging waves, matching
//   the m190 GEMM null/negative precedent) -- removed.
// Session ledger (flash): 234 -> 224 (nt) -> 181 (V via LDS; VMEM
//   line-request wall, R17) -> 165.5 (K dbuf full-tile cover, R21).
//   Nulls: XCD-batch remap, occupancy 2->3 blk/CU. Negatives: mask->LDS,
//   setprio, 16-row tiles. Failed-correctness (3/3, abandoned): deep
//   prefetch wait schemes (R14/R18/R23) -- on-paper vmcnt proofs
//   insufficient, no bisection in this loop.
// R21 structure: 256 WGs x 512 thr (8 waves, 1 blk/CU). batch=(bx&7)>>1,
//   q0=((bx>>3)*2+(bx&1))*64. K double-buffered (staged at tile TOP into
//   alternate buffer, full-tile cover); V single-buffered (staged TOP,
//   waited at E). Per tile t:
//   TOP stage V(t)->Vlds (4) + K(t+1)->Klds[(t+1)&1] (4) ->
//   QK from Klds[t&1] -> P=exp2(masked S) (mask regs) -> B2 (lgkm0+bar)
//   -> M(t+2) NT -> E vmcnt(12)+bar [retires M(t+1)+V(t)] -> PV -> B1
//   vmcnt(8)+bar [K(t+1) landed; M(t+2) flies].
// ws: Qs bf16 8MiB | Kb bf16 8MiB | Vt bf16 8MiB | Wp 384KiB

#define DEV static __device__ __forceinline__

typedef __attribute__((ext_vector_type(8))) short bf8;   // 8 bf16 (4 VGPR)
typedef __attribute__((ext_vector_type(4))) float f4;
typedef const __attribute__((address_space(1))) unsigned int* gp1;
typedef __attribute__((address_space(3))) unsigned int* lp3;

DEV short f2bf(float x) {  // fp32 -> bf16 RNE (inputs finite)
  unsigned u = __builtin_bit_cast(unsigned, x);
  u += 0x7FFFu + ((u >> 16) & 1u);
  return (short)(u >> 16);
}

DEV bf8 cvt8(f4 a, f4 b) {
  bf8 r;
  r[0] = f2bf(a[0]); r[1] = f2bf(a[1]); r[2] = f2bf(a[2]); r[3] = f2bf(a[3]);
  r[4] = f2bf(b[0]); r[5] = f2bf(b[1]); r[6] = f2bf(b[2]); r[7] = f2bf(b[3]);
  return r;
}

DEV bf8 cvtp(const float* p) { return cvt8(*(const f4*)p, *(const f4*)(p + 4)); }

DEV f4 mfma16(bf8 a, bf8 b, f4 c) {
  return __builtin_amdgcn_mfma_f32_16x16x32_bf16(a, b, c, 0, 0, 0);
}

DEV void gl_lds16(const void* g, void* l) {  // async global->LDS, 16B/lane
  __builtin_amdgcn_global_load_lds((gp1)g, (lp3)l, 16, 0, 0);
}

DEV void ld16(bf8& d, const short* p) {  // unsinkable 16B global load
  __asm__ __volatile__("global_load_dwordx4 %0, %1, off" : "=v"(d) : "v"(p));
}
DEV void ld4nt(int& d, const int* p) {   // unsinkable 4B global load, NT
  __asm__ __volatile__("global_load_dword %0, %1, off nt" : "=v"(d) : "v"(p));
}

// ---------------- kernel 0: pack W -> bf16 fragment-order (R9) ------------
__global__ void pack(const float* __restrict__ Wq, const float* __restrict__ Wk,
                     const float* __restrict__ Wv, short* __restrict__ Wp) {
  const int ch = blockIdx.x * 4 + (threadIdx.x >> 6);
  const int lane = threadIdx.x & 63;
  const int which = ch >> 7, rem = ch & 127;
  const int w = rem >> 5, e = (rem >> 3) & 3, ks = rem & 7;
  const float* W = (which == 0) ? Wq : (which == 1) ? Wk : Wv;
  bf8 v = cvtp(W + ((w * 4 + e) * 16 + (lane & 15)) * 256 + ks * 32 +
               (lane >> 4) * 8);
  *(bf8*)(Wp + ch * 512 + lane * 8) = v;
}

// ---------------- kernel 1: Q,K,V projection (R9) -------------------------
__launch_bounds__(256, 3)
__global__ void qkv(const float* __restrict__ x, const short* __restrict__ Wp,
                    const float* __restrict__ bq, const float* __restrict__ bk,
                    const float* __restrict__ bv, short* __restrict__ Qs,
                    short* __restrict__ Kb, short* __restrict__ Vt) {
  __shared__ float Xf[32 * 256];    // x tile, swizzled, 32KB
  __shared__ short Vlds[256 * 36];  // V transpose staging (which==2 only)
  const int which = blockIdx.y;
  const int m0 = blockIdx.x * 32;
  const int tid = threadIdx.x;
  const int w = tid >> 6, lane = tid & 63, quad = lane >> 4, c = lane & 15;
  const float* bias = (which == 0) ? bq : (which == 1) ? bk : bv;

#pragma unroll
  for (int l = 0; l < 8; l++) {
    const int row = l * 4 + (tid >> 6);
    const int kch = tid & 63;
    const int chg = (kch & 48) | ((kch ^ (row & 15)) & 15);  // involutive
    gl_lds16(x + (m0 + row) * 256 + chg * 4, &Xf[(l * 256 + tid) * 4]);
  }

  float bb[4];
#pragma unroll
  for (int e = 0; e < 4; e++) bb[e] = bias[(w * 4 + e) * 16 + c];

  f4 acc[2][4];
  const f4 z = {0.f, 0.f, 0.f, 0.f};
#pragma unroll
  for (int i = 0; i < 2; i++)
#pragma unroll
    for (int j = 0; j < 4; j++) acc[i][j] = z;

  __asm__ __volatile__("s_waitcnt vmcnt(0)\ns_barrier" ::: "memory");

  const short* wpb = Wp + (which * 4 + w) * 4 * 8 * 512;
#pragma unroll
  for (int ks = 0; ks < 8; ks++) {
    bf8 a[2], b[4];
#pragma unroll
    for (int ms = 0; ms < 2; ms++) {  // A[m=lane&15][k=quad*8+j]
      const int m = ms * 16 + c;
      const int ch0 = ks * 8 + quad * 2;
      const int sw0 = (ch0 & 48) | ((ch0 ^ c) & 15);
      const int sw1 = ((ch0 + 1) & 48) | (((ch0 + 1) ^ c) & 15);
      f4 f0 = *(const f4*)&Xf[m * 256 + sw0 * 4];
      f4 f1 = *(const f4*)&Xf[m * 256 + sw1 * 4];
      a[ms] = cvt8(f0, f1);
    }
#pragma unroll
    for (int e = 0; e < 4; e++)
      b[e] = *(const bf8*)(wpb + (e * 8 + ks) * 512 + lane * 8);
#pragma unroll
    for (int ms = 0; ms < 2; ms++)
#pragma unroll
      for (int e = 0; e < 4; e++) acc[ms][e] = mfma16(a[ms], b[e], acc[ms][e]);
  }

  const float sc = (which == 0) ? 0.09016844005556021f : 1.0f;  // log2e/16

  if (which < 2) {
    short* dst = (which == 0) ? Qs : Kb;
#pragma unroll
    for (int ms = 0; ms < 2; ms++)
#pragma unroll
      for (int e = 0; e < 4; e++)
#pragma unroll
        for (int r = 0; r < 4; r++)  // C/D: col=lane&15, row=quad*4+reg
          dst[(m0 + ms * 16 + quad * 4 + r) * 256 + (w * 4 + e) * 16 + c] =
              f2bf((acc[ms][e][r] + bb[e]) * sc);
  } else {
#pragma unroll
    for (int ms = 0; ms < 2; ms++)
#pragma unroll
      for (int e = 0; e < 4; e++)
#pragma unroll
        for (int r = 0; r < 4; r++)
          Vlds[((w * 4 + e) * 16 + c) * 36 + ms * 16 + quad * 4 + r] =
              f2bf(acc[ms][e][r] + bb[e]);
    __syncthreads();
    const int tt = m0 >> 6, half = m0 & 32;
#pragma unroll
    for (int j = 0; j < 4; j++) {
      int flat = j * 2048 + tid * 8;        // 256 d x 32 n
      int d = flat >> 5, n = flat & 31;
      *(bf8*)(Vt + tt * 16384 + d * 64 + half + n) =
          *(const bf8*)&Vlds[d * 36 + n];
    }
  }
}

// ---------------- kernel 2: flash attention ----------------
// 256 WGs x 512 threads (8 waves, 1 block/CU). batch = (bx&7)>>1,
// q0 = ((bx>>3)*2+(bx&1))*64 (bijective). Wave w8: h = w8>>2 (q-rows
// h*32..+31), wc = w8&3 (cols wc*64..+63 for PV/out, k-cols wc*16..+15).
// K double-buffered; V single; per tile t:
//  TOP: stage V(t)->Vlds (4) + K(t+1)->Klds[(t+1)&1] (4) ->
//  QK from Klds[t&1] -> P=exp2(masked S) (mask regs) -> B2 (lgkm0+bar)
//  -> issue M(t+2) NT -> E vmcnt(12)+bar [retires M(t+1)+V(t); K+M fly]
//  -> PV (V,P from LDS) -> B1 vmcnt(8)+bar [K(t+1) landed; M(t+2) flies].
__launch_bounds__(512, 1)
__global__ void flash(const short* __restrict__ Qs, const short* __restrict__ Kb,
                      const short* __restrict__ Vt, const int* __restrict__ mask,
                      float* __restrict__ out) {
  __shared__ short Klds[2][16384];  // K dbuf 64x256, swizzled, 64KB
  __shared__ short Vlds[16384];     // V [256 d][64 k], swizzled, 32KB
  __shared__ short Plds[64 * 76];   // P 64 rows, stride 76 (conflict-free)
  const int bx = blockIdx.x;
  const int batch = (bx & 7) >> 1;                  // XCD pair -> batch
  const int q0 = ((bx >> 3) * 2 + (bx & 1)) * 64;   // bijective q-tile
  const int tid = threadIdx.x;
  const int lane = tid & 63, quad = lane >> 4, c = lane & 15;
  const int w8 = tid >> 6, h = w8 >> 2, wc = w8 & 3;

  const short* kb = Kb + batch * 4096 * 256;
  const short* vb = Vt + batch * 1048576;
  const int* mb = mask + batch * 16777216;

  const int krow = tid >> 5;  // K staging row-in-16-row-line (0..15)
  const int kch = tid & 31;   // LDS chunk this thread fills

  // ---- prologue: K(0)->Klds[0], M(0)->mA, M(1)->mB, Q via asm ----
#pragma unroll
  for (int l = 0; l < 4; l++) {
    const int row = l * 16 + krow;
    const int chg = (kch & 16) | ((kch ^ row) & 15);  // involutive swizzle
    gl_lds16(kb + row * 256 + chg * 8, &Klds[0][l * 4096 + tid * 8]);
  }
  int mA[8], mB[8];
#pragma unroll
  for (int ms = 0; ms < 2; ms++)
#pragma unroll
    for (int r = 0; r < 4; r++) {
      const int qr = q0 + h * 32 + ms * 16 + quad * 4 + r;
      ld4nt(mA[ms * 4 + r], mb + qr * 4096 + wc * 16 + c);
      ld4nt(mB[ms * 4 + r], mb + qr * 4096 + 64 + wc * 16 + c);
    }
  bf8 aq[2][8];
  const short* qb = Qs + (batch * 4096 + q0) * 256;
#pragma unroll
  for (int ms = 0; ms < 2; ms++)
#pragma unroll
    for (int ks = 0; ks < 8; ks++)
      ld16(aq[ms][ks], qb + (h * 32 + ms * 16 + c) * 256 + ks * 32 + quad * 8);

  const f4 z = {0.f, 0.f, 0.f, 0.f};
  f4 accO[2][4], lacc[2];
#pragma unroll
  for (int ms = 0; ms < 2; ms++) {
    lacc[ms] = z;
#pragma unroll
    for (int ds = 0; ds < 4; ds++) accO[ms][ds] = z;
  }
  const bf8 ONES = {0x3F80, 0x3F80, 0x3F80, 0x3F80, 0x3F80, 0x3F80, 0x3F80, 0x3F80};

  // drain prologue; tie aq on the waitcnt, masks on a follow-up tie asm
  __asm__ __volatile__("s_waitcnt vmcnt(0)\ns_barrier"
      : "+v"(aq[0][0]), "+v"(aq[0][1]), "+v"(aq[0][2]), "+v"(aq[0][3]),
        "+v"(aq[0][4]), "+v"(aq[0][5]), "+v"(aq[0][6]), "+v"(aq[0][7]),
        "+v"(aq[1][0]), "+v"(aq[1][1]), "+v"(aq[1][2]), "+v"(aq[1][3]),
        "+v"(aq[1][4]), "+v"(aq[1][5]), "+v"(aq[1][6]), "+v"(aq[1][7])
      :: "memory");
  __asm__ __volatile__(""
      : "+v"(mA[0]), "+v"(mA[1]), "+v"(mA[2]), "+v"(mA[3]),
        "+v"(mA[4]), "+v"(mA[5]), "+v"(mA[6]), "+v"(mA[7]),
        "+v"(mB[0]), "+v"(mB[1]), "+v"(mB[2]), "+v"(mB[3]),
        "+v"(mB[4]), "+v"(mB[5]), "+v"(mB[6]), "+v"(mB[7]) :: "memory");

  auto tile = [&](int t, int* mcur) {
    // ---- TOP: stage V(t) -> Vlds (WAR safe: PV(t-1) reads done at
    //      B1(t-1)); then K(t+1) -> Klds[(t+1)&1] (WAR safe: that buffer
    //      last read at QK(t-1), complete at B2(t-1)). Issue order V
    //      before K keeps the E/B1 retire sets identical to R19. ----
    const short* vbt = vb + t * 16384;
#pragma unroll
    for (int l = 0; l < 4; l++) {
      const int flat = l * 512 + tid;      // 0..2047, 16B each
      const int d = flat >> 3, ck = flat & 7;
      gl_lds16(vbt + d * 64 + ((ck ^ (d & 7)) << 3), &Vlds[flat * 8]);
    }
    const int tk = (t < 63) ? t + 1 : 63;
    const short* kbt = kb + tk * 16384;
    short* kst = &Klds[(t + 1) & 1][0];
#pragma unroll
    for (int l = 0; l < 4; l++) {
      const int row = l * 16 + krow;
      const int chg = (kch & 16) | ((kch ^ row) & 15);
      gl_lds16(kbt + row * 256 + chg * 8, &kst[l * 4096 + tid * 8]);
    }

    // ---- S = Q' K^T from Klds[t&1] (proven landed at B1(t-1)) ----
    const short* krd = &Klds[t & 1][0];
    f4 s[2];
#pragma unroll
    for (int ms = 0; ms < 2; ms++) s[ms] = z;
#pragma unroll
    for (int ks = 0; ks < 8; ks++) {
      const int ch = ks * 4 + quad;
      const int sw = (ch & 16) | ((ch ^ c) & 15);
      const bf8 kf = *(const bf8*)&krd[(wc * 16 + c) * 256 + sw * 8];
#pragma unroll
      for (int ms = 0; ms < 2; ms++) s[ms] = mfma16(aq[ms][ks], kf, s[ms]);
    }

    // ---- P = exp2(masked S) -> Plds (mask regs retired by prev E) ----
    short* pw = &Plds[0];
#pragma unroll
    for (int ms = 0; ms < 2; ms++)
#pragma unroll
      for (int r = 0; r < 4; r++) {
        float sv = (mcur[ms * 4 + r] != 0) ? s[ms][r] : -INFINITY;
        pw[(h * 32 + ms * 16 + quad * 4 + r) * 76 + wc * 16 + c] =
            f2bf(__builtin_amdgcn_exp2f(sv));
      }
    // B2: P visible; all QK reads of Klds[t&1] complete across the block
    __asm__ __volatile__("s_waitcnt lgkmcnt(0)\ns_barrier" ::: "memory");

    // ---- issue M(t+2) into mcur (P reads above done; reg WAR orders) ----
    const int tm = (t + 2 < 64) ? t + 2 : 63;
#pragma unroll
    for (int ms = 0; ms < 2; ms++)
#pragma unroll
      for (int r = 0; r < 4; r++)
        ld4nt(mcur[ms * 4 + r],
              mb + (q0 + h * 32 + ms * 16 + quad * 4 + r) * 4096 + tm * 64 +
                  wc * 16 + c);

    // ---- E: queue=[M(t+1):8,V(t):4,K(t+1):4,M(t+2):8]=24; vmcnt(12)
    //      retires M(t+1)+V(t); leaves K4+M8 flying; barrier -> V(t)
    //      visible block-wide ----
    __asm__ __volatile__("s_waitcnt vmcnt(12)\ns_barrier"
        : "+v"(mA[0]), "+v"(mA[1]), "+v"(mA[2]), "+v"(mA[3]),
          "+v"(mA[4]), "+v"(mA[5]), "+v"(mA[6]), "+v"(mA[7]),
          "+v"(mB[0]), "+v"(mB[1]), "+v"(mB[2]), "+v"(mB[3]),
          "+v"(mB[4]), "+v"(mB[5]), "+v"(mB[6]), "+v"(mB[7]) :: "memory");

    // ---- O += P V ; row-sum via ones-frag MFMA. V frags from Vlds:
    //      lane reads Vlds[d=wc*64+ds*16+c][(k2*4+quad)^(c&7) chunk] ----
#pragma unroll
    for (int k2 = 0; k2 < 2; k2++) {
      bf8 ap[2], vf[4];
#pragma unroll
      for (int ds = 0; ds < 4; ds++)
        vf[ds] = *(const bf8*)&Vlds[(wc * 64 + ds * 16 + c) * 64 +
                                    (((k2 * 4 + quad) ^ (c & 7)) << 3)];
#pragma unroll
      for (int ms = 0; ms < 2; ms++)  // A[m=lane&15][k=quad*8+j]
        ap[ms] = *(const bf8*)&pw[(h * 32 + ms * 16 + c) * 76 + k2 * 32 +
                                  quad * 8];
#pragma unroll
      for (int ms = 0; ms < 2; ms++) {
        lacc[ms] = mfma16(ap[ms], ONES, lacc[ms]);
#pragma unroll
        for (int ds = 0; ds < 4; ds++)
          accO[ms][ds] = mfma16(ap[ms], vf[ds], accO[ms][ds]);
      }
    }
    // B1: vmcnt(8) retires K(t+1) (leaves M(t+2) flying); barrier ->
    // K(t+1) visible for next tile's QK; Vlds/Plds free for overwrite
    __asm__ __volatile__("s_waitcnt vmcnt(8)\ns_barrier" ::: "memory");
  };

  for (int th = 0; th < 32; th++) {
    tile(2 * th, mA);
    tile(2 * th + 1, mB);
  }
  // drain in-flight tail M loads before epilogue reuses their registers
  __asm__ __volatile__("s_waitcnt vmcnt(0)" ::: "memory");

  // ---- epilogue: O / l (in-register, deterministic) ----
  float* ob = out + (batch * 4096 + q0) * 256;
#pragma unroll
  for (int ms = 0; ms < 2; ms++) {
    f4 rl;
#pragma unroll
    for (int r = 0; r < 4; r++) rl[r] = __builtin_amdgcn_rcpf(lacc[ms][r]);
#pragma unroll
    for (int ds = 0; ds < 4; ds++)
#pragma unroll
      for (int r = 0; r < 4; r++)
        ob[(h * 32 + ms * 16 + quad * 4 + r) * 256 + wc * 64 + ds * 16 + c] =
            accO[ms][ds][r] * rl[r];
  }
}

extern "C" void kernel_launch(void* const* d_in, const int* in_sizes, int n_in,
                              void* d_out, int out_size, void* d_ws, size_t ws_size,
                              hipStream_t stream) {
  const float* x = (const float*)d_in[0];
  const int* mask = (const int*)d_in[1];
  const float* Wq = (const float*)d_in[2];
  const float* bq = (const float*)d_in[3];
  const float* Wk = (const float*)d_in[4];
  const float* bk = (const float*)d_in[5];
  const float* Wv = (const float*)d_in[6];
  const float* bv = (const float*)d_in[7];
  float* out = (float*)d_out;

  char* ws = (char*)d_ws;  // 24 MiB + 384 KiB
  short* Qs = (short*)ws;
  short* Kb = (short*)(ws + (8u << 20));
  short* Vt = (short*)(ws + (16u << 20));
  short* Wp = (short*)(ws + (24u << 20));

  pack<<<96, 256, 0, stream>>>(Wq, Wk, Wv, Wp);
  qkv<<<dim3(512, 3), 256, 0, stream>>>(x, Wp, bq, bk, bv, Qs, Kb, Vt);
  flash<<<256, 512, 0, stream>>>(Qs, Kb, Vt, mask, out);
}

// Round 16
// 469.577 us; speedup vs baseline: 1.0454x; 1.0227x over previous
//
#include <hip/hip_runtime.h>

// Self-attention, B=4, N=4096, D=256 (single head over full D).
//   Q = x Wq^T + bq ; K,V likewise ; S = Q K^T ; mask==0 -> -inf ;
//   attn = softmax(S/16) ; out = attn V        (fp32 in/out)
// R26 = R21 with B2 MERGED into E (3 -> 2 barriers/tile). This is the
//   only remaining lever with VMEM bookkeeping BIT-IDENTICAL to the
//   proven R21: same issue order, same queue compositions, same
//   vmcnt(12)/vmcnt(8) retire sets at E/B1 (t=0 + t=63 edges re-checked).
//   Only change: B2's lgkmcnt(0)+barrier is folded into E ->
//   "s_waitcnt vmcnt(12) lgkmcnt(0); s_barrier". Guarantees preserved:
//   P visible before PV (merged lgkm0+bar = B2's guarantee, same point
//   rel. to PV); QK reads of Klds[t&1] complete before consuming MFMAs
//   issue << B1(t) < TOP(t+1) overwrite; Plds/Vlds WAR via B1 unchanged.
//   NOT the failed R14/R18/R23 class (those changed staging depth /
//   retire sets; this changes neither).
// Ledger (flash): 234 -> 224 (nt) -> 181 (V via LDS, R17) -> 165.5
//   (K dbuf, R21). Nulls: XCD remap, occupancy. Negatives: mask->LDS,
//   setprio, 16-row tiles. Abandoned (3/3 absmax fails): deep prefetch.
// ws: Qs bf16 8MiB | Kb bf16 8MiB | Vt bf16 8MiB | Wp 384KiB

#define DEV static __device__ __forceinline__

typedef __attribute__((ext_vector_type(8))) short bf8;   // 8 bf16 (4 VGPR)
typedef __attribute__((ext_vector_type(4))) float f4;
typedef const __attribute__((address_space(1))) unsigned int* gp1;
typedef __attribute__((address_space(3))) unsigned int* lp3;

DEV short f2bf(float x) {  // fp32 -> bf16 RNE (inputs finite)
  unsigned u = __builtin_bit_cast(unsigned, x);
  u += 0x7FFFu + ((u >> 16) & 1u);
  return (short)(u >> 16);
}

DEV bf8 cvt8(f4 a, f4 b) {
  bf8 r;
  r[0] = f2bf(a[0]); r[1] = f2bf(a[1]); r[2] = f2bf(a[2]); r[3] = f2bf(a[3]);
  r[4] = f2bf(b[0]); r[5] = f2bf(b[1]); r[6] = f2bf(b[2]); r[7] = f2bf(b[3]);
  return r;
}

DEV bf8 cvtp(const float* p) { return cvt8(*(const f4*)p, *(const f4*)(p + 4)); }

DEV f4 mfma16(bf8 a, bf8 b, f4 c) {
  return __builtin_amdgcn_mfma_f32_16x16x32_bf16(a, b, c, 0, 0, 0);
}

DEV void gl_lds16(const void* g, void* l) {  // async global->LDS, 16B/lane
  __builtin_amdgcn_global_load_lds((gp1)g, (lp3)l, 16, 0, 0);
}

DEV void ld16(bf8& d, const short* p) {  // unsinkable 16B global load
  __asm__ __volatile__("global_load_dwordx4 %0, %1, off" : "=v"(d) : "v"(p));
}
DEV void ld4nt(int& d, const int* p) {   // unsinkable 4B global load, NT
  __asm__ __volatile__("global_load_dword %0, %1, off nt" : "=v"(d) : "v"(p));
}

// ---------------- kernel 0: pack W -> bf16 fragment-order (R9) ------------
__global__ void pack(const float* __restrict__ Wq, const float* __restrict__ Wk,
                     const float* __restrict__ Wv, short* __restrict__ Wp) {
  const int ch = blockIdx.x * 4 + (threadIdx.x >> 6);
  const int lane = threadIdx.x & 63;
  const int which = ch >> 7, rem = ch & 127;
  const int w = rem >> 5, e = (rem >> 3) & 3, ks = rem & 7;
  const float* W = (which == 0) ? Wq : (which == 1) ? Wk : Wv;
  bf8 v = cvtp(W + ((w * 4 + e) * 16 + (lane & 15)) * 256 + ks * 32 +
               (lane >> 4) * 8);
  *(bf8*)(Wp + ch * 512 + lane * 8) = v;
}

// ---------------- kernel 1: Q,K,V projection (R9) -------------------------
__launch_bounds__(256, 3)
__global__ void qkv(const float* __restrict__ x, const short* __restrict__ Wp,
                    const float* __restrict__ bq, const float* __restrict__ bk,
                    const float* __restrict__ bv, short* __restrict__ Qs,
                    short* __restrict__ Kb, short* __restrict__ Vt) {
  __shared__ float Xf[32 * 256];    // x tile, swizzled, 32KB
  __shared__ short Vlds[256 * 36];  // V transpose staging (which==2 only)
  const int which = blockIdx.y;
  const int m0 = blockIdx.x * 32;
  const int tid = threadIdx.x;
  const int w = tid >> 6, lane = tid & 63, quad = lane >> 4, c = lane & 15;
  const float* bias = (which == 0) ? bq : (which == 1) ? bk : bv;

#pragma unroll
  for (int l = 0; l < 8; l++) {
    const int row = l * 4 + (tid >> 6);
    const int kch = tid & 63;
    const int chg = (kch & 48) | ((kch ^ (row & 15)) & 15);  // involutive
    gl_lds16(x + (m0 + row) * 256 + chg * 4, &Xf[(l * 256 + tid) * 4]);
  }

  float bb[4];
#pragma unroll
  for (int e = 0; e < 4; e++) bb[e] = bias[(w * 4 + e) * 16 + c];

  f4 acc[2][4];
  const f4 z = {0.f, 0.f, 0.f, 0.f};
#pragma unroll
  for (int i = 0; i < 2; i++)
#pragma unroll
    for (int j = 0; j < 4; j++) acc[i][j] = z;

  __asm__ __volatile__("s_waitcnt vmcnt(0)\ns_barrier" ::: "memory");

  const short* wpb = Wp + (which * 4 + w) * 4 * 8 * 512;
#pragma unroll
  for (int ks = 0; ks < 8; ks++) {
    bf8 a[2], b[4];
#pragma unroll
    for (int ms = 0; ms < 2; ms++) {  // A[m=lane&15][k=quad*8+j]
      const int m = ms * 16 + c;
      const int ch0 = ks * 8 + quad * 2;
      const int sw0 = (ch0 & 48) | ((ch0 ^ c) & 15);
      const int sw1 = ((ch0 + 1) & 48) | (((ch0 + 1) ^ c) & 15);
      f4 f0 = *(const f4*)&Xf[m * 256 + sw0 * 4];
      f4 f1 = *(const f4*)&Xf[m * 256 + sw1 * 4];
      a[ms] = cvt8(f0, f1);
    }
#pragma unroll
    for (int e = 0; e < 4; e++)
      b[e] = *(const bf8*)(wpb + (e * 8 + ks) * 512 + lane * 8);
#pragma unroll
    for (int ms = 0; ms < 2; ms++)
#pragma unroll
      for (int e = 0; e < 4; e++) acc[ms][e] = mfma16(a[ms], b[e], acc[ms][e]);
  }

  const float sc = (which == 0) ? 0.09016844005556021f : 1.0f;  // log2e/16

  if (which < 2) {
    short* dst = (which == 0) ? Qs : Kb;
#pragma unroll
    for (int ms = 0; ms < 2; ms++)
#pragma unroll
      for (int e = 0; e < 4; e++)
#pragma unroll
        for (int r = 0; r < 4; r++)  // C/D: col=lane&15, row=quad*4+reg
          dst[(m0 + ms * 16 + quad * 4 + r) * 256 + (w * 4 + e) * 16 + c] =
              f2bf((acc[ms][e][r] + bb[e]) * sc);
  } else {
#pragma unroll
    for (int ms = 0; ms < 2; ms++)
#pragma unroll
      for (int e = 0; e < 4; e++)
#pragma unroll
        for (int r = 0; r < 4; r++)
          Vlds[((w * 4 + e) * 16 + c) * 36 + ms * 16 + quad * 4 + r] =
              f2bf(acc[ms][e][r] + bb[e]);
    __syncthreads();
    const int tt = m0 >> 6, half = m0 & 32;
#pragma unroll
    for (int j = 0; j < 4; j++) {
      int flat = j * 2048 + tid * 8;        // 256 d x 32 n
      int d = flat >> 5, n = flat & 31;
      *(bf8*)(Vt + tt * 16384 + d * 64 + half + n) =
          *(const bf8*)&Vlds[d * 36 + n];
    }
  }
}

// ---------------- kernel 2: flash attention ----------------
// 256 WGs x 512 threads (8 waves, 1 block/CU). batch = (bx&7)>>1,
// q0 = ((bx>>3)*2+(bx&1))*64 (bijective). Wave w8: h = w8>>2 (q-rows
// h*32..+31), wc = w8&3 (cols wc*64..+63 for PV/out, k-cols wc*16..+15).
// K double-buffered; V single; per tile t (2 barriers):
//  TOP: stage V(t)->Vlds (4) + K(t+1)->Klds[(t+1)&1] (4) ->
//  QK from Klds[t&1] -> P=exp2(masked S) (mask regs) -> issue M(t+2) NT
//  -> E' [s_waitcnt vmcnt(12) lgkmcnt(0); s_barrier]: P visible AND V(t)
//  landed AND M(t+1) retired (vmcnt queue identical to R21's E) ->
//  PV (V,P from LDS) -> B1 vmcnt(8)+bar [K(t+1) landed; M(t+2) flies].
__launch_bounds__(512, 1)
__global__ void flash(const short* __restrict__ Qs, const short* __restrict__ Kb,
                      const short* __restrict__ Vt, const int* __restrict__ mask,
                      float* __restrict__ out) {
  __shared__ short Klds[2][16384];  // K dbuf 64x256, swizzled, 64KB
  __shared__ short Vlds[16384];     // V [256 d][64 k], swizzled, 32KB
  __shared__ short Plds[64 * 76];   // P 64 rows, stride 76 (conflict-free)
  const int bx = blockIdx.x;
  const int batch = (bx & 7) >> 1;                  // XCD pair -> batch
  const int q0 = ((bx >> 3) * 2 + (bx & 1)) * 64;   // bijective q-tile
  const int tid = threadIdx.x;
  const int lane = tid & 63, quad = lane >> 4, c = lane & 15;
  const int w8 = tid >> 6, h = w8 >> 2, wc = w8 & 3;

  const short* kb = Kb + batch * 4096 * 256;
  const short* vb = Vt + batch * 1048576;
  const int* mb = mask + batch * 16777216;

  const int krow = tid >> 5;  // K staging row-in-16-row-line (0..15)
  const int kch = tid & 31;   // LDS chunk this thread fills

  // ---- prologue: K(0)->Klds[0], M(0)->mA, M(1)->mB, Q via asm ----
#pragma unroll
  for (int l = 0; l < 4; l++) {
    const int row = l * 16 + krow;
    const int chg = (kch & 16) | ((kch ^ row) & 15);  // involutive swizzle
    gl_lds16(kb + row * 256 + chg * 8, &Klds[0][l * 4096 + tid * 8]);
  }
  int mA[8], mB[8];
#pragma unroll
  for (int ms = 0; ms < 2; ms++)
#pragma unroll
    for (int r = 0; r < 4; r++) {
      const int qr = q0 + h * 32 + ms * 16 + quad * 4 + r;
      ld4nt(mA[ms * 4 + r], mb + qr * 4096 + wc * 16 + c);
      ld4nt(mB[ms * 4 + r], mb + qr * 4096 + 64 + wc * 16 + c);
    }
  bf8 aq[2][8];
  const short* qb = Qs + (batch * 4096 + q0) * 256;
#pragma unroll
  for (int ms = 0; ms < 2; ms++)
#pragma unroll
    for (int ks = 0; ks < 8; ks++)
      ld16(aq[ms][ks], qb + (h * 32 + ms * 16 + c) * 256 + ks * 32 + quad * 8);

  const f4 z = {0.f, 0.f, 0.f, 0.f};
  f4 accO[2][4], lacc[2];
#pragma unroll
  for (int ms = 0; ms < 2; ms++) {
    lacc[ms] = z;
#pragma unroll
    for (int ds = 0; ds < 4; ds++) accO[ms][ds] = z;
  }
  const bf8 ONES = {0x3F80, 0x3F80, 0x3F80, 0x3F80, 0x3F80, 0x3F80, 0x3F80, 0x3F80};

  // drain prologue; tie aq on the waitcnt, masks on a follow-up tie asm
  __asm__ __volatile__("s_waitcnt vmcnt(0)\ns_barrier"
      : "+v"(aq[0][0]), "+v"(aq[0][1]), "+v"(aq[0][2]), "+v"(aq[0][3]),
        "+v"(aq[0][4]), "+v"(aq[0][5]), "+v"(aq[0][6]), "+v"(aq[0][7]),
        "+v"(aq[1][0]), "+v"(aq[1][1]), "+v"(aq[1][2]), "+v"(aq[1][3]),
        "+v"(aq[1][4]), "+v"(aq[1][5]), "+v"(aq[1][6]), "+v"(aq[1][7])
      :: "memory");
  __asm__ __volatile__(""
      : "+v"(mA[0]), "+v"(mA[1]), "+v"(mA[2]), "+v"(mA[3]),
        "+v"(mA[4]), "+v"(mA[5]), "+v"(mA[6]), "+v"(mA[7]),
        "+v"(mB[0]), "+v"(mB[1]), "+v"(mB[2]), "+v"(mB[3]),
        "+v"(mB[4]), "+v"(mB[5]), "+v"(mB[6]), "+v"(mB[7]) :: "memory");

  auto tile = [&](int t, int* mcur) {
    // ---- TOP: stage V(t) -> Vlds (WAR safe: PV(t-1) reads done at
    //      B1(t-1)); then K(t+1) -> Klds[(t+1)&1] (WAR safe: that buffer
    //      last read at QK(t-1), reads complete before their consuming
    //      MFMAs issued, << B1(t-1)). Issue order V-then-K keeps the
    //      E'/B1 retire sets identical to R21. ----
    const short* vbt = vb + t * 16384;
#pragma unroll
    for (int l = 0; l < 4; l++) {
      const int flat = l * 512 + tid;      // 0..2047, 16B each
      const int d = flat >> 3, ck = flat & 7;
      gl_lds16(vbt + d * 64 + ((ck ^ (d & 7)) << 3), &Vlds[flat * 8]);
    }
    const int tk = (t < 63) ? t + 1 : 63;
    const short* kbt = kb + tk * 16384;
    short* kst = &Klds[(t + 1) & 1][0];
#pragma unroll
    for (int l = 0; l < 4; l++) {
      const int row = l * 16 + krow;
      const int chg = (kch & 16) | ((kch ^ row) & 15);
      gl_lds16(kbt + row * 256 + chg * 8, &kst[l * 4096 + tid * 8]);
    }

    // ---- S = Q' K^T from Klds[t&1] (proven landed at B1(t-1)) ----
    const short* krd = &Klds[t & 1][0];
    f4 s[2];
#pragma unroll
    for (int ms = 0; ms < 2; ms++) s[ms] = z;
#pragma unroll
    for (int ks = 0; ks < 8; ks++) {
      const int ch = ks * 4 + quad;
      const int sw = (ch & 16) | ((ch ^ c) & 15);
      const bf8 kf = *(const bf8*)&krd[(wc * 16 + c) * 256 + sw * 8];
#pragma unroll
      for (int ms = 0; ms < 2; ms++) s[ms] = mfma16(aq[ms][ks], kf, s[ms]);
    }

    // ---- P = exp2(masked S) -> Plds (mask regs retired by prev E') ----
    short* pw = &Plds[0];
#pragma unroll
    for (int ms = 0; ms < 2; ms++)
#pragma unroll
      for (int r = 0; r < 4; r++) {
        float sv = (mcur[ms * 4 + r] != 0) ? s[ms][r] : -INFINITY;
        pw[(h * 32 + ms * 16 + quad * 4 + r) * 76 + wc * 16 + c] =
            f2bf(__builtin_amdgcn_exp2f(sv));
      }

    // ---- issue M(t+2) into mcur (P read mcur above; reg WAR orders;
    //      no LDS ops here so P-visibility unaffected) ----
    const int tm = (t + 2 < 64) ? t + 2 : 63;
#pragma unroll
    for (int ms = 0; ms < 2; ms++)
#pragma unroll
      for (int r = 0; r < 4; r++)
        ld4nt(mcur[ms * 4 + r],
              mb + (q0 + h * 32 + ms * 16 + quad * 4 + r) * 4096 + tm * 64 +
                  wc * 16 + c);

    // ---- E' (merged B2+E): queue=[M(t+1):8,V(t):4,K(t+1):4,M(t+2):8]
    //      =24; vmcnt(12) retires M(t+1)+V(t) (identical to R21's E);
    //      lgkmcnt(0) = B2's P-write drain; barrier -> P AND V(t)
    //      visible block-wide; QK reads of Klds[t&1] long done ----
    __asm__ __volatile__("s_waitcnt vmcnt(12) lgkmcnt(0)\ns_barrier"
        : "+v"(mA[0]), "+v"(mA[1]), "+v"(mA[2]), "+v"(mA[3]),
          "+v"(mA[4]), "+v"(mA[5]), "+v"(mA[6]), "+v"(mA[7]),
          "+v"(mB[0]), "+v"(mB[1]), "+v"(mB[2]), "+v"(mB[3]),
          "+v"(mB[4]), "+v"(mB[5]), "+v"(mB[6]), "+v"(mB[7]) :: "memory");

    // ---- O += P V ; row-sum via ones-frag MFMA. V frags from Vlds:
    //      lane reads Vlds[d=wc*64+ds*16+c][(k2*4+quad)^(c&7) chunk] ----
#pragma unroll
    for (int k2 = 0; k2 < 2; k2++) {
      bf8 ap[2], vf[4];
#pragma unroll
      for (int ds = 0; ds < 4; ds++)
        vf[ds] = *(const bf8*)&Vlds[(wc * 64 + ds * 16 + c) * 64 +
                                    (((k2 * 4 + quad) ^ (c & 7)) << 3)];
#pragma unroll
      for (int ms = 0; ms < 2; ms++)  // A[m=lane&15][k=quad*8+j]
        ap[ms] = *(const bf8*)&pw[(h * 32 + ms * 16 + c) * 76 + k2 * 32 +
                                  quad * 8];
#pragma unroll
      for (int ms = 0; ms < 2; ms++) {
        lacc[ms] = mfma16(ap[ms], ONES, lacc[ms]);
#pragma unroll
        for (int ds = 0; ds < 4; ds++)
          accO[ms][ds] = mfma16(ap[ms], vf[ds], accO[ms][ds]);
      }
    }
    // B1: vmcnt(8) retires K(t+1) (leaves M(t+2) flying); barrier ->
    // K(t+1) visible for next tile's QK; Vlds/Plds free for overwrite
    // (PV LDS reads completed before their consuming MFMAs issued)
    __asm__ __volatile__("s_waitcnt vmcnt(8)\ns_barrier" ::: "memory");
  };

  for (int th = 0; th < 32; th++) {
    tile(2 * th, mA);
    tile(2 * th + 1, mB);
  }
  // drain in-flight tail M loads before epilogue reuses their registers
  __asm__ __volatile__("s_waitcnt vmcnt(0)" ::: "memory");

  // ---- epilogue: O / l (in-register, deterministic) ----
  float* ob = out + (batch * 4096 + q0) * 256;
#pragma unroll
  for (int ms = 0; ms < 2; ms++) {
    f4 rl;
#pragma unroll
    for (int r = 0; r < 4; r++) rl[r] = __builtin_amdgcn_rcpf(lacc[ms][r]);
#pragma unroll
    for (int ds = 0; ds < 4; ds++)
#pragma unroll
      for (int r = 0; r < 4; r++)
        ob[(h * 32 + ms * 16 + quad * 4 + r) * 256 + wc * 64 + ds * 16 + c] =
            accO[ms][ds][r] * rl[r];
  }
}

extern "C" void kernel_launch(void* const* d_in, const int* in_sizes, int n_in,
                              void* d_out, int out_size, void* d_ws, size_t ws_size,
                              hipStream_t stream) {
  const float* x = (const float*)d_in[0];
  const int* mask = (const int*)d_in[1];
  const float* Wq = (const float*)d_in[2];
  const float* bq = (const float*)d_in[3];
  const float* Wk = (const float*)d_in[4];
  const float* bk = (const float*)d_in[5];
  const float* Wv = (const float*)d_in[6];
  const float* bv = (const float*)d_in[7];
  float* out = (float*)d_out;

  char* ws = (char*)d_ws;  // 24 MiB + 384 KiB
  short* Qs = (short*)ws;
  short* Kb = (short*)(ws + (8u << 20));
  short* Vt = (short*)(ws + (16u << 20));
  short* Wp = (short*)(ws + (24u << 20));

  pack<<<96, 256, 0, stream>>>(Wq, Wk, Wv, Wp);
  qkv<<<dim3(512, 3), 256, 0, stream>>>(x, Wp, bq, bk, bv, Qs, Kb, Vt);
  flash<<<256, 512, 0, stream>>>(Qs, Kb, Vt, mask, out);
}